// Round 1
// baseline (230.172 us; speedup 1.0000x reference)
//
#include <hip/hip_runtime.h>

// Problem constants
#define NHEADS   8
#define EMB_     128
#define BT_      512        // b*t = 4*128
#define HIN_     1024
#define NQ_      4096       // BT_*NHEADS
#define NKEY_    50000
#define NPAD_    50048      // 782 tiles of 64 keys
#define TILES_TOT 782
#define TPS_     25         // key tiles per slice
#define NSLICES_ 32         // ceil(782/25): 31 full + 1 slice of 7 tiles

// scale = 128^-0.25 (reference) * log2(e) (so MFMA scores are already in exp2 domain)
#define QSCALE   (0.29730177875068026f * 1.4426950408889634f)
#define SHIFT_   44.0f      // fixed softmax shift in log2 domain (~30.5 nats, > max score ~21 nats)

typedef __attribute__((ext_vector_type(8))) short short8v;   // 8 bf16 = 4 VGPRs (MFMA A/B frag)
typedef __attribute__((ext_vector_type(4))) float float4v;   // MFMA C/D frag

#if __has_builtin(__builtin_amdgcn_exp2f)
#define EXP2F(x) __builtin_amdgcn_exp2f(x)
#else
#define EXP2F(x) exp2f(x)
#endif

__device__ __forceinline__ short f2bf(float f) {  // fp32 -> bf16 bits, RNE
  unsigned u = __float_as_uint(f);
  u += 0x7fffu + ((u >> 16) & 1u);
  return (short)(u >> 16);
}

// ---------------------------------------------------------------------------
// Kernel 0: keys fp32 -> bf16 with XOR chunk swizzle + zero-pad; values padded.
// Physical 16B chunk p of row `key` holds logical chunk (p ^ (key&15)).
// This makes the attention kernel's per-quad B-frag ds_read_b128 2-way max
// (free per m136) instead of 16-way on the 256B row stride.
// ---------------------------------------------------------------------------
__global__ __launch_bounds__(256) void convert_kernel(
    const float* __restrict__ keys, const float* __restrict__ values,
    short* __restrict__ keys_sw, float* __restrict__ vpad) {
  int idx = blockIdx.x * 256 + threadIdx.x;      // one thread per 8-elem chunk
  if (idx >= NPAD_ * 16) return;
  int key = idx >> 4;
  int p   = idx & 15;
  int lc  = p ^ (key & 15);                      // logical chunk stored here
  short8v o;
  if (key < NKEY_) {
    const float* src = keys + key * EMB_ + lc * 8;
#pragma unroll
    for (int i = 0; i < 8; ++i) o[i] = f2bf(src[i]);
  } else {
#pragma unroll
    for (int i = 0; i < 8; ++i) o[i] = 0;        // pad rows -> score 0 -> p=2^-44, negligible
  }
  *(short8v*)(keys_sw + idx * 8) = o;            // coalesced 16B stores
  if (p == 0) vpad[key] = (key < NKEY_) ? values[key] : 0.f;
}

// ---------------------------------------------------------------------------
// Kernel 1: q = (x @ Wq^T) * QSCALE, output bf16 [BT_][1024] == [q-head][128].
// fp32 LDS-tiled GEMM (accuracy headroom; only 1.07 GF). Tile 32m x 64n, K=16.
// ---------------------------------------------------------------------------
__global__ __launch_bounds__(256) void proj_kernel(
    const float* __restrict__ x, const float* __restrict__ Wq,
    short* __restrict__ qb) {
  __shared__ float xs[32][17];   // +1 pad: conflict-free
  __shared__ float wsh[64][17];
  const int t  = threadIdx.x;
  const int m0 = blockIdx.x * 32;   // grid.x = 16
  const int o0 = blockIdx.y * 64;   // grid.y = 16
  const int c  = (t & 15) * 4;      // 4 output cols
  const int r  = (t >> 4) * 2;      // 2 output rows
  float acc[2][4] = {{0.f,0.f,0.f,0.f},{0.f,0.f,0.f,0.f}};

  for (int k0 = 0; k0 < HIN_; k0 += 16) {
    __syncthreads();
    if (t < 128) {                               // stage x tile: 32x16 fp32
      int rr = t >> 2, kc = (t & 3) * 4;
      float4 v = *(const float4*)(x + (m0 + rr) * HIN_ + k0 + kc);
      xs[rr][kc] = v.x; xs[rr][kc+1] = v.y; xs[rr][kc+2] = v.z; xs[rr][kc+3] = v.w;
    }
    {                                            // stage Wq tile: 64x16 fp32
      int rr = t >> 2, kc = (t & 3) * 4;
      float4 v = *(const float4*)(Wq + (o0 + rr) * HIN_ + k0 + kc);
      wsh[rr][kc] = v.x; wsh[rr][kc+1] = v.y; wsh[rr][kc+2] = v.z; wsh[rr][kc+3] = v.w;
    }
    __syncthreads();
#pragma unroll
    for (int kk = 0; kk < 16; ++kk) {
      float x0 = xs[r][kk], x1 = xs[r+1][kk];
      float w0 = wsh[c][kk], w1 = wsh[c+1][kk], w2 = wsh[c+2][kk], w3 = wsh[c+3][kk];
      acc[0][0] += x0*w0; acc[0][1] += x0*w1; acc[0][2] += x0*w2; acc[0][3] += x0*w3;
      acc[1][0] += x1*w0; acc[1][1] += x1*w1; acc[1][2] += x1*w2; acc[1][3] += x1*w3;
    }
  }
#pragma unroll
  for (int i = 0; i < 2; ++i)
#pragma unroll
    for (int j = 0; j < 4; ++j)
      qb[(m0 + r + i) * HIN_ + o0 + c + j] = f2bf(acc[i][j] * QSCALE);
}

// ---------------------------------------------------------------------------
// Kernel 2: flash-decoding attention. Grid (16 query-cols, 32 key-slices).
// Per WG: 256 queries (4 waves x 4 sub-tiles of 16, A-frags register-resident),
// stream 64-key tiles via LDS. MFMA 16x16x32 bf16:
//   A: lane m=ln, k=quad*8+j  |  B: lane n=ln, k=quad*8+j  |  D: row=quad*4+reg, col=ln
// Softmax: p = exp2(score' - 44) (score' already in log2 domain) -> no max pass.
// Per-lane (l,acc) partials over its key-columns; 16-lane butterfly at slice end.
// ---------------------------------------------------------------------------
__global__ __launch_bounds__(256, 2) void attn_kernel(
    const short* __restrict__ qb,        // bf16 [NQ_][128]
    const short* __restrict__ keys_sw,   // bf16 [NPAD_][128], chunk-swizzled
    const float* __restrict__ vpad,      // [NPAD_]
    float* __restrict__ partials) {      // [NQ_][NSLICES_][2] = {l, acc}
  __shared__ __align__(16) short kt[64 * 128];   // 16 KB key tile
  const int t     = threadIdx.x;
  const int wave  = t >> 6;
  const int lane  = t & 63;
  const int quad  = lane >> 4;
  const int ln    = lane & 15;
  const int qbase = blockIdx.x * 256 + wave * 64;
  const int slice = blockIdx.y;
  const int tile0 = slice * TPS_;
  const int tile1 = (tile0 + TPS_ < TILES_TOT) ? (tile0 + TPS_) : TILES_TOT;

  // A fragments, register resident: a[sub][ks] covers q rows qbase+sub*16+ln, e = ks*32+quad*8..+7
  short8v a[4][4];
#pragma unroll
  for (int sub = 0; sub < 4; ++sub)
#pragma unroll
    for (int ks = 0; ks < 4; ++ks)
      a[sub][ks] = *(const short8v*)(qb + (qbase + sub * 16 + ln) * EMB_ + ks * 32 + quad * 8);

  float lsum[4][4], asum[4][4];
#pragma unroll
  for (int i = 0; i < 4; ++i)
#pragma unroll
    for (int j = 0; j < 4; ++j) { lsum[i][j] = 0.f; asum[i][j] = 0.f; }

  for (int tile = tile0; tile < tile1; ++tile) {
    __syncthreads();
    const short* src = keys_sw + tile * (64 * 128);
#pragma unroll
    for (int j = 0; j < 4; ++j) {                // stage 16 KB: 256 thr x 4 x 16B, coalesced
      int cidx = t + j * 256;
      *(short8v*)(kt + cidx * 8) = *(const short8v*)(src + cidx * 8);
    }
    __syncthreads();

#pragma unroll
    for (int nsub = 0; nsub < 4; ++nsub) {
      short8v b[4];
#pragma unroll
      for (int ks = 0; ks < 4; ++ks) {
        int kc = ks * 4 + quad;                  // logical 8-elem chunk
        b[ks] = *(const short8v*)(kt + (nsub * 16 + ln) * EMB_ + ((kc ^ ln) * 8));
      }
      float v = vpad[tile * 64 + nsub * 16 + ln];  // value for this lane's key column
#pragma unroll
      for (int sub = 0; sub < 4; ++sub) {
        float4v d = {0.f, 0.f, 0.f, 0.f};
#pragma unroll
        for (int ks = 0; ks < 4; ++ks)
          d = __builtin_amdgcn_mfma_f32_16x16x32_bf16(a[sub][ks], b[ks], d, 0, 0, 0);
#pragma unroll
        for (int r2 = 0; r2 < 4; ++r2) {
          float p = EXP2F(d[r2] - SHIFT_);
          lsum[sub][r2] += p;
          asum[sub][r2] += p * v;
        }
      }
    }
  }

  // reduce over the 16 key-column lanes (same quad), then lane ln==0 writes
#pragma unroll
  for (int sub = 0; sub < 4; ++sub)
#pragma unroll
    for (int r2 = 0; r2 < 4; ++r2) {
      float L = lsum[sub][r2], A = asum[sub][r2];
#pragma unroll
      for (int m = 1; m < 16; m <<= 1) {
        L += __shfl_xor(L, m, 64);
        A += __shfl_xor(A, m, 64);
      }
      if (ln == 0) {
        int q = qbase + sub * 16 + quad * 4 + r2;
        partials[(q * NSLICES_ + slice) * 2 + 0] = L;
        partials[(q * NSLICES_ + slice) * 2 + 1] = A;
      }
    }
}

// ---------------------------------------------------------------------------
// Kernel 3: combine slice partials, mean over heads, add curiosity.
// ---------------------------------------------------------------------------
__global__ __launch_bounds__(256) void finalize_kernel(
    const float* __restrict__ partials, const float* __restrict__ cur,
    float* __restrict__ out) {
  int bt = blockIdx.x * 256 + threadIdx.x;
  if (bt >= BT_) return;
  float r = 0.f;
#pragma unroll
  for (int h = 0; h < NHEADS; ++h) {
    int qi = bt * NHEADS + h;
    float sl = 0.f, sa = 0.f;
    const float* p = partials + qi * NSLICES_ * 2;
#pragma unroll 8
    for (int s = 0; s < NSLICES_; ++s) { sl += p[2*s]; sa += p[2*s + 1]; }
    r += sa / sl;
  }
  out[bt] = r * (1.f / NHEADS) + cur[bt];
}

// ---------------------------------------------------------------------------
extern "C" void kernel_launch(void* const* d_in, const int* in_sizes, int n_in,
                              void* d_out, int out_size, void* d_ws, size_t ws_size,
                              hipStream_t stream) {
  (void)in_sizes; (void)n_in; (void)out_size; (void)ws_size;
  const float* x      = (const float*)d_in[0];   // (4,128,1024)
  const float* cur    = (const float*)d_in[1];   // (4,128)
  const float* Wq     = (const float*)d_in[2];   // (1024,1024)
  const float* keys   = (const float*)d_in[3];   // (50000,128)
  const float* values = (const float*)d_in[4];   // (50000,)
  float* out = (float*)d_out;                    // (4,128,1) fp32

  // workspace layout (all 256B-aligned): ~14.5 MB total
  char* ws = (char*)d_ws;
  short* keys_sw = (short*)(ws);                        // 12,812,288 B
  float* vpad    = (float*)(ws + 12812288);             //    200,192 B
  short* qb      = (short*)(ws + 13012480);             //  1,048,576 B
  float* part    = (float*)(ws + 14061056);             //  1,048,576 B

  hipLaunchKernelGGL(convert_kernel, dim3((NPAD_ * 16) / 256), dim3(256), 0, stream,
                     keys, values, keys_sw, vpad);
  hipLaunchKernelGGL(proj_kernel, dim3(16, 16), dim3(256), 0, stream, x, Wq, qb);
  hipLaunchKernelGGL(attn_kernel, dim3(16, NSLICES_), dim3(256), 0, stream,
                     qb, keys_sw, vpad, part);
  hipLaunchKernelGGL(finalize_kernel, dim3(2), dim3(256), 0, stream, part, cur, out);
}